// Round 4
// baseline (403.159 us; speedup 1.0000x reference)
//
#include <hip/hip_runtime.h>
#include <hip/hip_fp16.h>

// Tri-plane importance-renderer sampling.
// planes: [N=4][P=3][C=32][H=256][W=256] f32
// coords: [N][M=500000][3] f32, directions unused.
// out:    [N][M][C] f32  = mean over P of bilinear samples (zeros padding,
//                          align_corners=False).
// Plane->grid mapping (from inv(_PLANES)): p0:(cx,cy)  p1:(cx,cz)  p2:(cz,cx)
//
// R3 insight: gather is bound by the on-chip RANDOM-ACCESS path (warm replays:
// 261us at 0.26GB HBM -> L3-resident but no faster). Fix locality, not bytes:
// Morton-sort samples (counting sort, 32^3 cells) so a wave touches ~2 cells
// -> corner reads become L1/L2 hits. Output scatters 128B records to original
// slots (deterministic: each sample writes only its own slot).

constexpr int Cc = 32, Hh = 256, Ww = 256, Pp = 3, Nn = 4;
constexpr int HWPIX = Hh * Ww;   // 65536
constexpr int NCELLS = 32768;    // 32^3 Morton cells

// ---------------------------------------------------------------------------
// Morton key helpers: 5 bits per axis, interleaved -> 15-bit key.
// ---------------------------------------------------------------------------
__device__ inline unsigned spread3(unsigned x) {
    x &= 0x3FFu;
    x = (x | (x << 16)) & 0x030000FFu;
    x = (x | (x << 8))  & 0x0300F00Fu;
    x = (x | (x << 4))  & 0x030C30C3u;
    x = (x | (x << 2))  & 0x09249249u;
    return x;
}
__device__ inline unsigned morton_key(float cx, float cy, float cz) {
    const int a = min(max((int)((cx + 1.0f) * 16.0f), 0), 31);
    const int b = min(max((int)((cy + 1.0f) * 16.0f), 0), 31);
    const int c = min(max((int)((cz + 1.0f) * 16.0f), 0), 31);
    return spread3((unsigned)a) | (spread3((unsigned)b) << 1) | (spread3((unsigned)c) << 2);
}

// ---------------------------------------------------------------------------
// Pass 1: transpose+convert [slice][C][HW] f32 -> [slice][HW][C] fp16.
// ---------------------------------------------------------------------------
__global__ __launch_bounds__(256) void transpose_chw_hwc_h(
    const float* __restrict__ in, __half* __restrict__ out)
{
    __shared__ float lds[Cc * 257];
    const int slice = blockIdx.y;
    const int pix0  = blockIdx.x * 256;
    const int t     = threadIdx.x;

    const float* src = in + (size_t)slice * Cc * HWPIX + pix0 + t;
    #pragma unroll
    for (int c = 0; c < Cc; ++c)
        lds[c * 257 + t] = src[(size_t)c * HWPIX];
    __syncthreads();

    uint4* dst = reinterpret_cast<uint4*>(
        out + (size_t)slice * HWPIX * Cc + (size_t)pix0 * Cc);
    #pragma unroll
    for (int k = 0; k < 4; ++k) {
        const int idx = k * 256 + t;
        const int pix = idx >> 2;
        const int c0  = (idx & 3) * 8;
        unsigned r[4];
        #pragma unroll
        for (int j = 0; j < 4; ++j) {
            const __half h0 = __float2half(lds[(c0 + 2 * j + 0) * 257 + pix]);
            const __half h1 = __float2half(lds[(c0 + 2 * j + 1) * 257 + pix]);
            r[j] = (unsigned)__half_as_ushort(h0)
                 | ((unsigned)__half_as_ushort(h1) << 16);
        }
        dst[idx] = make_uint4(r[0], r[1], r[2], r[3]);
    }
}

// ---------------------------------------------------------------------------
// Sort pipeline: zero -> histogram -> exclusive scan -> scatter records.
// Record = {cx, cy, cz, bitcast(orig_m)} float4.
// ---------------------------------------------------------------------------
__global__ __launch_bounds__(256) void zero_u32(unsigned* __restrict__ p, int n)
{
    const int i = blockIdx.x * 256 + threadIdx.x;
    if (i < n) p[i] = 0u;
}

__global__ __launch_bounds__(256) void hist_kernel(
    const float* __restrict__ coords, unsigned* __restrict__ hist, int M)
{
    const int m = blockIdx.x * 256 + threadIdx.x;
    const int n = blockIdx.y;
    if (m >= M) return;
    const float* cp = coords + ((size_t)n * M + m) * 3;
    const unsigned key = morton_key(cp[0], cp[1], cp[2]);
    atomicAdd(&hist[n * NCELLS + key], 1u);
}

__global__ __launch_bounds__(1024) void scan_kernel(unsigned* __restrict__ hist)
{
    __shared__ unsigned lds[1024];
    unsigned* h = hist + (size_t)blockIdx.x * NCELLS;
    const int t = threadIdx.x;
    unsigned v[32];
    unsigned s = 0;
    #pragma unroll
    for (int i = 0; i < 32; ++i) { v[i] = h[t * 32 + i]; s += v[i]; }
    lds[t] = s;
    __syncthreads();
    // Hillis-Steele inclusive scan over 1024 partials.
    for (int d = 1; d < 1024; d <<= 1) {
        const unsigned add = (t >= d) ? lds[t - d] : 0u;
        __syncthreads();
        lds[t] += add;
        __syncthreads();
    }
    unsigned base = (t > 0) ? lds[t - 1] : 0u;   // exclusive offset
    #pragma unroll
    for (int i = 0; i < 32; ++i) { const unsigned tmp = v[i]; h[t * 32 + i] = base; base += tmp; }
}

__global__ __launch_bounds__(256) void scatter_kernel(
    const float* __restrict__ coords, unsigned* __restrict__ hist,
    float4* __restrict__ rec, int M)
{
    const int m = blockIdx.x * 256 + threadIdx.x;
    const int n = blockIdx.y;
    if (m >= M) return;
    const float* cp = coords + ((size_t)n * M + m) * 3;
    const float cx = cp[0], cy = cp[1], cz = cp[2];
    const unsigned key = morton_key(cx, cy, cz);
    const unsigned pos = atomicAdd(&hist[n * NCELLS + key], 1u);
    float4 r;
    r.x = cx; r.y = cy; r.z = cz; r.w = __int_as_float(m);
    rec[(size_t)n * M + pos] = r;
}

// ---------------------------------------------------------------------------
// Gather in Morton order. 8 lanes per sample (one 8B fp16 chunk each).
// 1D grid + bijective XCD-chunked swizzle: each XCD sweeps a contiguous
// Morton range -> active L2 window ~4MB.
// ---------------------------------------------------------------------------
__global__ __launch_bounds__(256) void triplane_gather_sorted(
    const __half* __restrict__ tp, const float4* __restrict__ rec,
    float* __restrict__ out, int M, int gx, int nwg)
{
    int bid = blockIdx.x;
    {   // bijective chunked XCD swizzle (m204 form)
        const int q = nwg >> 3, r = nwg & 7;
        const int xcd = bid & 7, idx = bid >> 3;
        bid = (xcd < r ? xcd * (q + 1) : r * (q + 1) + (xcd - r) * q) + idx;
    }
    const int n  = bid / gx;
    const int bx = bid - n * gx;
    const int gid   = bx * 256 + threadIdx.x;
    const int s     = gid >> 3;
    const int chunk = gid & 7;
    if (s >= M) return;

    const float4 rc = rec[(size_t)n * M + s];
    const float cx = rc.x, cy = rc.y, cz = rc.z;
    const int   m  = __float_as_int(rc.w);

    const uint2* addr[12];
    float w[12];

    #pragma unroll
    for (int p = 0; p < 3; ++p) {
        const float gxc = (p == 2) ? cz : cx;
        const float gyc = (p == 0) ? cy : ((p == 1) ? cz : cx);
        // exact reference op order: ((g+1)*S - 1) * 0.5
        const float x = ((gxc + 1.0f) * 256.0f - 1.0f) * 0.5f;
        const float y = ((gyc + 1.0f) * 256.0f - 1.0f) * 0.5f;
        const float x0f = floorf(x), y0f = floorf(y);
        const float wx = x - x0f, wy = y - y0f;
        const int x0 = (int)x0f, y0 = (int)y0f;
        const int x1 = x0 + 1,   y1 = y0 + 1;
        const bool vx0 = (unsigned)x0 < 256u;
        const bool vx1 = (unsigned)x1 < 256u;
        const bool vy0 = (unsigned)y0 < 256u;
        const bool vy1 = (unsigned)y1 < 256u;
        const int cx0 = min(max(x0, 0), 255), cx1 = min(max(x1, 0), 255);
        const int cy0 = min(max(y0, 0), 255), cy1 = min(max(y1, 0), 255);

        w[p * 4 + 0] = ((vx0 && vy0) ? 1.f : 0.f) * (1.f - wx) * (1.f - wy);
        w[p * 4 + 1] = ((vx1 && vy0) ? 1.f : 0.f) * wx * (1.f - wy);
        w[p * 4 + 2] = ((vx0 && vy1) ? 1.f : 0.f) * (1.f - wx) * wy;
        w[p * 4 + 3] = ((vx1 && vy1) ? 1.f : 0.f) * wx * wy;

        const uint2* base = reinterpret_cast<const uint2*>(
            tp + (size_t)(n * 3 + p) * HWPIX * Cc);
        addr[p * 4 + 0] = base + (size_t)((cy0 << 8) + cx0) * 8 + chunk;
        addr[p * 4 + 1] = base + (size_t)((cy0 << 8) + cx1) * 8 + chunk;
        addr[p * 4 + 2] = base + (size_t)((cy1 << 8) + cx0) * 8 + chunk;
        addr[p * 4 + 3] = base + (size_t)((cy1 << 8) + cx1) * 8 + chunk;
    }

    uint2 rv[12];
    #pragma unroll
    for (int j = 0; j < 12; ++j) rv[j] = *addr[j];

    float4 acc = make_float4(0.f, 0.f, 0.f, 0.f);
    #pragma unroll
    for (int j = 0; j < 12; ++j) {
        const __half2 h0 = *reinterpret_cast<const __half2*>(&rv[j].x);
        const __half2 h1 = *reinterpret_cast<const __half2*>(&rv[j].y);
        const float2 f0 = __half22float2(h0);
        const float2 f1 = __half22float2(h1);
        acc.x += w[j] * f0.x;
        acc.y += w[j] * f0.y;
        acc.z += w[j] * f1.x;
        acc.w += w[j] * f1.y;
    }

    constexpr float third = 1.0f / 3.0f;
    acc.x *= third; acc.y *= third; acc.z *= third; acc.w *= third;

    float4* op = reinterpret_cast<float4*>(out + ((size_t)n * M + m) * Cc);
    op[chunk] = acc;
}

// ---------------------------------------------------------------------------
// Mid tier (ws fits planes only): unsorted fp16 gather (R3 kernel).
// ---------------------------------------------------------------------------
__global__ __launch_bounds__(256) void triplane_gather_hwc8h(
    const __half* __restrict__ tp, const float* __restrict__ coords,
    float* __restrict__ out, int M)
{
    const int gid   = blockIdx.x * 256 + threadIdx.x;
    const int m     = gid >> 3;
    const int chunk = gid & 7;
    const int n     = blockIdx.y;
    if (m >= M) return;

    const float* cp = coords + ((size_t)n * M + m) * 3;
    const float cx = cp[0], cy = cp[1], cz = cp[2];

    const uint2* addr[12];
    float w[12];

    #pragma unroll
    for (int p = 0; p < 3; ++p) {
        const float gxc = (p == 2) ? cz : cx;
        const float gyc = (p == 0) ? cy : ((p == 1) ? cz : cx);
        const float x = ((gxc + 1.0f) * 256.0f - 1.0f) * 0.5f;
        const float y = ((gyc + 1.0f) * 256.0f - 1.0f) * 0.5f;
        const float x0f = floorf(x), y0f = floorf(y);
        const float wx = x - x0f, wy = y - y0f;
        const int x0 = (int)x0f, y0 = (int)y0f;
        const int x1 = x0 + 1,   y1 = y0 + 1;
        const bool vx0 = (unsigned)x0 < 256u;
        const bool vx1 = (unsigned)x1 < 256u;
        const bool vy0 = (unsigned)y0 < 256u;
        const bool vy1 = (unsigned)y1 < 256u;
        const int cx0 = min(max(x0, 0), 255), cx1 = min(max(x1, 0), 255);
        const int cy0 = min(max(y0, 0), 255), cy1 = min(max(y1, 0), 255);

        w[p * 4 + 0] = ((vx0 && vy0) ? 1.f : 0.f) * (1.f - wx) * (1.f - wy);
        w[p * 4 + 1] = ((vx1 && vy0) ? 1.f : 0.f) * wx * (1.f - wy);
        w[p * 4 + 2] = ((vx0 && vy1) ? 1.f : 0.f) * (1.f - wx) * wy;
        w[p * 4 + 3] = ((vx1 && vy1) ? 1.f : 0.f) * wx * wy;

        const uint2* base = reinterpret_cast<const uint2*>(
            tp + (size_t)(n * 3 + p) * HWPIX * Cc);
        addr[p * 4 + 0] = base + (size_t)((cy0 << 8) + cx0) * 8 + chunk;
        addr[p * 4 + 1] = base + (size_t)((cy0 << 8) + cx1) * 8 + chunk;
        addr[p * 4 + 2] = base + (size_t)((cy1 << 8) + cx0) * 8 + chunk;
        addr[p * 4 + 3] = base + (size_t)((cy1 << 8) + cx1) * 8 + chunk;
    }

    uint2 rv[12];
    #pragma unroll
    for (int j = 0; j < 12; ++j) rv[j] = *addr[j];

    float4 acc = make_float4(0.f, 0.f, 0.f, 0.f);
    #pragma unroll
    for (int j = 0; j < 12; ++j) {
        const __half2 h0 = *reinterpret_cast<const __half2*>(&rv[j].x);
        const __half2 h1 = *reinterpret_cast<const __half2*>(&rv[j].y);
        const float2 f0 = __half22float2(h0);
        const float2 f1 = __half22float2(h1);
        acc.x += w[j] * f0.x;
        acc.y += w[j] * f0.y;
        acc.z += w[j] * f1.x;
        acc.w += w[j] * f1.y;
    }

    constexpr float third = 1.0f / 3.0f;
    acc.x *= third; acc.y *= third; acc.z *= third; acc.w *= third;

    float4* op = reinterpret_cast<float4*>(out + ((size_t)n * M + m) * Cc);
    op[chunk] = acc;
}

// ---------------------------------------------------------------------------
// Fallback (no workspace): gather straight from [C][H][W] f32 layout.
// ---------------------------------------------------------------------------
__global__ __launch_bounds__(256) void triplane_gather_chw(
    const float* __restrict__ planes, const float* __restrict__ coords,
    float* __restrict__ out, int M)
{
    const int m = blockIdx.x * 256 + threadIdx.x;
    const int n = blockIdx.y;
    if (m >= M) return;

    const float* cp = coords + ((size_t)n * M + m) * 3;
    const float cx = cp[0], cy = cp[1], cz = cp[2];

    int   off[3][4];
    float w[3][4];
    #pragma unroll
    for (int p = 0; p < 3; ++p) {
        const float gxc = (p == 2) ? cz : cx;
        const float gyc = (p == 0) ? cy : ((p == 1) ? cz : cx);
        const float x = ((gxc + 1.0f) * 256.0f - 1.0f) * 0.5f;
        const float y = ((gyc + 1.0f) * 256.0f - 1.0f) * 0.5f;
        const float x0f = floorf(x), y0f = floorf(y);
        const float wx = x - x0f, wy = y - y0f;
        const int x0 = (int)x0f, y0 = (int)y0f;
        const int x1 = x0 + 1,   y1 = y0 + 1;
        const bool vx0 = (unsigned)x0 < 256u, vx1 = (unsigned)x1 < 256u;
        const bool vy0 = (unsigned)y0 < 256u, vy1 = (unsigned)y1 < 256u;
        const int cx0 = min(max(x0, 0), 255), cx1 = min(max(x1, 0), 255);
        const int cy0 = min(max(y0, 0), 255), cy1 = min(max(y1, 0), 255);
        off[p][0] = (cy0 << 8) + cx0;  w[p][0] = ((vx0 && vy0) ? 1.f : 0.f) * (1.f - wx) * (1.f - wy);
        off[p][1] = (cy0 << 8) + cx1;  w[p][1] = ((vx1 && vy0) ? 1.f : 0.f) * wx * (1.f - wy);
        off[p][2] = (cy1 << 8) + cx0;  w[p][2] = ((vx0 && vy1) ? 1.f : 0.f) * (1.f - wx) * wy;
        off[p][3] = (cy1 << 8) + cx1;  w[p][3] = ((vx1 && vy1) ? 1.f : 0.f) * wx * wy;
    }

    float* op = out + ((size_t)n * M + m) * Cc;
    constexpr float third = 1.0f / 3.0f;
    for (int c = 0; c < Cc; ++c) {
        float a = 0.f;
        #pragma unroll
        for (int p = 0; p < 3; ++p) {
            const float* b = planes + ((size_t)(n * 3 + p) * Cc + c) * HWPIX;
            a += w[p][0] * b[off[p][0]] + w[p][1] * b[off[p][1]]
               + w[p][2] * b[off[p][2]] + w[p][3] * b[off[p][3]];
        }
        op[c] = a * third;
    }
}

extern "C" void kernel_launch(void* const* d_in, const int* in_sizes, int n_in,
                              void* d_out, int out_size, void* d_ws, size_t ws_size,
                              hipStream_t stream)
{
    const float* planes = (const float*)d_in[0];
    const float* coords = (const float*)d_in[1];
    float* out = (float*)d_out;

    const int M = in_sizes[1] / (Nn * 3);           // 500000

    const size_t tp_bytes   = (size_t)Nn * Pp * HWPIX * Cc * sizeof(__half);   // ~50 MB
    const size_t rec_bytes  = (size_t)Nn * M * sizeof(float4);                 // ~32 MB
    const size_t hist_bytes = (size_t)Nn * NCELLS * sizeof(unsigned);          // 0.5 MB

    if (ws_size >= tp_bytes + rec_bytes + hist_bytes) {
        __half*   tp   = (__half*)d_ws;
        float4*   rec  = (float4*)((char*)d_ws + tp_bytes);
        unsigned* hist = (unsigned*)((char*)d_ws + tp_bytes + rec_bytes);

        transpose_chw_hwc_h<<<dim3(HWPIX / 256, Nn * Pp), 256, 0, stream>>>(planes, tp);
        zero_u32<<<(Nn * NCELLS + 255) / 256, 256, 0, stream>>>(hist, Nn * NCELLS);
        hist_kernel<<<dim3((M + 255) / 256, Nn), 256, 0, stream>>>(coords, hist, M);
        scan_kernel<<<Nn, 1024, 0, stream>>>(hist);
        scatter_kernel<<<dim3((M + 255) / 256, Nn), 256, 0, stream>>>(coords, hist, rec, M);

        const int gx  = (M * 8 + 255) / 256;   // 8 lanes per sample
        const int nwg = Nn * gx;
        triplane_gather_sorted<<<nwg, 256, 0, stream>>>(tp, rec, out, M, gx, nwg);
    } else if (ws_size >= tp_bytes) {
        __half* tp = (__half*)d_ws;
        transpose_chw_hwc_h<<<dim3(HWPIX / 256, Nn * Pp), 256, 0, stream>>>(planes, tp);
        const int gx = (M * 8 + 255) / 256;
        triplane_gather_hwc8h<<<dim3(gx, Nn), 256, 0, stream>>>(tp, coords, out, M);
    } else {
        const int gx = (M + 255) / 256;
        triplane_gather_chw<<<dim3(gx, Nn), 256, 0, stream>>>(planes, coords, out, M);
    }
}

// Round 5
// 395.234 us; speedup vs baseline: 1.0201x; 1.0201x over previous
//
#include <hip/hip_runtime.h>
#include <hip/hip_fp16.h>

// Tri-plane importance-renderer sampling.
// planes: [N=4][P=3][C=32][H=256][W=256] f32
// coords: [N][M=500000][3] f32, directions unused.
// out:    [N][M][C] f32  = mean over P of bilinear samples (zeros padding,
//                          align_corners=False).
// Plane->grid mapping (from inv(_PLANES)): p0:(cx,cy)  p1:(cx,cz)  p2:(cz,cx)
//
// R4 insight: counting-sort locality works, but scattering 16B records cost
// 156us (127MB HBM writes: write-allocate amplification over a 32MB window).
// Fix: scatter only a 4B index (8MB total window, L2-resident); gather
// re-reads coords via the index (cheap, L2/L3-resident).

constexpr int Cc = 32, Hh = 256, Ww = 256, Pp = 3, Nn = 4;
constexpr int HWPIX = Hh * Ww;   // 65536
constexpr int NCELLS = 32768;    // 32^3 Morton cells

// ---------------------------------------------------------------------------
// Morton key helpers: 5 bits per axis, interleaved -> 15-bit key.
// ---------------------------------------------------------------------------
__device__ inline unsigned spread3(unsigned x) {
    x &= 0x3FFu;
    x = (x | (x << 16)) & 0x030000FFu;
    x = (x | (x << 8))  & 0x0300F00Fu;
    x = (x | (x << 4))  & 0x030C30C3u;
    x = (x | (x << 2))  & 0x09249249u;
    return x;
}
__device__ inline unsigned morton_key(float cx, float cy, float cz) {
    const int a = min(max((int)((cx + 1.0f) * 16.0f), 0), 31);
    const int b = min(max((int)((cy + 1.0f) * 16.0f), 0), 31);
    const int c = min(max((int)((cz + 1.0f) * 16.0f), 0), 31);
    return spread3((unsigned)a) | (spread3((unsigned)b) << 1) | (spread3((unsigned)c) << 2);
}

// ---------------------------------------------------------------------------
// Pass 1: transpose+convert [slice][C][HW] f32 -> [slice][HW][C] fp16.
// ---------------------------------------------------------------------------
__global__ __launch_bounds__(256) void transpose_chw_hwc_h(
    const float* __restrict__ in, __half* __restrict__ out)
{
    __shared__ float lds[Cc * 257];
    const int slice = blockIdx.y;
    const int pix0  = blockIdx.x * 256;
    const int t     = threadIdx.x;

    const float* src = in + (size_t)slice * Cc * HWPIX + pix0 + t;
    #pragma unroll
    for (int c = 0; c < Cc; ++c)
        lds[c * 257 + t] = src[(size_t)c * HWPIX];
    __syncthreads();

    uint4* dst = reinterpret_cast<uint4*>(
        out + (size_t)slice * HWPIX * Cc + (size_t)pix0 * Cc);
    #pragma unroll
    for (int k = 0; k < 4; ++k) {
        const int idx = k * 256 + t;
        const int pix = idx >> 2;
        const int c0  = (idx & 3) * 8;
        unsigned r[4];
        #pragma unroll
        for (int j = 0; j < 4; ++j) {
            const __half h0 = __float2half(lds[(c0 + 2 * j + 0) * 257 + pix]);
            const __half h1 = __float2half(lds[(c0 + 2 * j + 1) * 257 + pix]);
            r[j] = (unsigned)__half_as_ushort(h0)
                 | ((unsigned)__half_as_ushort(h1) << 16);
        }
        dst[idx] = make_uint4(r[0], r[1], r[2], r[3]);
    }
}

// ---------------------------------------------------------------------------
// Sort pipeline: zero -> histogram -> exclusive scan -> scatter 4B indices.
// ---------------------------------------------------------------------------
__global__ __launch_bounds__(256) void zero_u32(unsigned* __restrict__ p, int n)
{
    const int i = blockIdx.x * 256 + threadIdx.x;
    if (i < n) p[i] = 0u;
}

__global__ __launch_bounds__(256) void hist_kernel(
    const float* __restrict__ coords, unsigned* __restrict__ hist, int M)
{
    const int m = blockIdx.x * 256 + threadIdx.x;
    const int n = blockIdx.y;
    if (m >= M) return;
    const float* cp = coords + ((size_t)n * M + m) * 3;
    const unsigned key = morton_key(cp[0], cp[1], cp[2]);
    atomicAdd(&hist[n * NCELLS + key], 1u);
}

__global__ __launch_bounds__(1024) void scan_kernel(unsigned* __restrict__ hist)
{
    __shared__ unsigned lds[1024];
    unsigned* h = hist + (size_t)blockIdx.x * NCELLS;
    const int t = threadIdx.x;
    unsigned v[32];
    unsigned s = 0;
    #pragma unroll
    for (int i = 0; i < 32; ++i) { v[i] = h[t * 32 + i]; s += v[i]; }
    lds[t] = s;
    __syncthreads();
    for (int d = 1; d < 1024; d <<= 1) {
        const unsigned add = (t >= d) ? lds[t - d] : 0u;
        __syncthreads();
        lds[t] += add;
        __syncthreads();
    }
    unsigned base = (t > 0) ? lds[t - 1] : 0u;   // exclusive offset
    #pragma unroll
    for (int i = 0; i < 32; ++i) { const unsigned tmp = v[i]; h[t * 32 + i] = base; base += tmp; }
}

__global__ __launch_bounds__(256) void scatter_idx_kernel(
    const float* __restrict__ coords, unsigned* __restrict__ hist,
    unsigned* __restrict__ idx, int M)
{
    const int m = blockIdx.x * 256 + threadIdx.x;
    const int n = blockIdx.y;
    if (m >= M) return;
    const float* cp = coords + ((size_t)n * M + m) * 3;
    const unsigned key = morton_key(cp[0], cp[1], cp[2]);
    const unsigned pos = atomicAdd(&hist[n * NCELLS + key], 1u);
    idx[(size_t)n * M + pos] = (unsigned)m;   // 4B random write, 2MB/n window
}

// ---------------------------------------------------------------------------
// Gather in Morton order via index indirection. 8 lanes per sample.
// Bijective XCD-chunked swizzle keeps each XCD on a contiguous Morton range.
// ---------------------------------------------------------------------------
__global__ __launch_bounds__(256) void triplane_gather_sorted(
    const __half* __restrict__ tp, const unsigned* __restrict__ idx,
    const float* __restrict__ coords, float* __restrict__ out,
    int M, int gx, int nwg)
{
    int bid = blockIdx.x;
    {   // bijective chunked XCD swizzle (m204 form)
        const int q = nwg >> 3, r = nwg & 7;
        const int xcd = bid & 7, i = bid >> 3;
        bid = (xcd < r ? xcd * (q + 1) : r * (q + 1) + (xcd - r) * q) + i;
    }
    const int n  = bid / gx;
    const int bx = bid - n * gx;
    const int gid   = bx * 256 + threadIdx.x;
    const int s     = gid >> 3;
    const int chunk = gid & 7;
    if (s >= M) return;

    const int m = (int)idx[(size_t)n * M + s];
    const float* cp = coords + ((size_t)n * M + m) * 3;
    const float cx = cp[0], cy = cp[1], cz = cp[2];

    const uint2* addr[12];
    float w[12];

    #pragma unroll
    for (int p = 0; p < 3; ++p) {
        const float gxc = (p == 2) ? cz : cx;
        const float gyc = (p == 0) ? cy : ((p == 1) ? cz : cx);
        // exact reference op order: ((g+1)*S - 1) * 0.5
        const float x = ((gxc + 1.0f) * 256.0f - 1.0f) * 0.5f;
        const float y = ((gyc + 1.0f) * 256.0f - 1.0f) * 0.5f;
        const float x0f = floorf(x), y0f = floorf(y);
        const float wx = x - x0f, wy = y - y0f;
        const int x0 = (int)x0f, y0 = (int)y0f;
        const int x1 = x0 + 1,   y1 = y0 + 1;
        const bool vx0 = (unsigned)x0 < 256u;
        const bool vx1 = (unsigned)x1 < 256u;
        const bool vy0 = (unsigned)y0 < 256u;
        const bool vy1 = (unsigned)y1 < 256u;
        const int cx0 = min(max(x0, 0), 255), cx1 = min(max(x1, 0), 255);
        const int cy0 = min(max(y0, 0), 255), cy1 = min(max(y1, 0), 255);

        w[p * 4 + 0] = ((vx0 && vy0) ? 1.f : 0.f) * (1.f - wx) * (1.f - wy);
        w[p * 4 + 1] = ((vx1 && vy0) ? 1.f : 0.f) * wx * (1.f - wy);
        w[p * 4 + 2] = ((vx0 && vy1) ? 1.f : 0.f) * (1.f - wx) * wy;
        w[p * 4 + 3] = ((vx1 && vy1) ? 1.f : 0.f) * wx * wy;

        const uint2* base = reinterpret_cast<const uint2*>(
            tp + (size_t)(n * 3 + p) * HWPIX * Cc);
        addr[p * 4 + 0] = base + (size_t)((cy0 << 8) + cx0) * 8 + chunk;
        addr[p * 4 + 1] = base + (size_t)((cy0 << 8) + cx1) * 8 + chunk;
        addr[p * 4 + 2] = base + (size_t)((cy1 << 8) + cx0) * 8 + chunk;
        addr[p * 4 + 3] = base + (size_t)((cy1 << 8) + cx1) * 8 + chunk;
    }

    uint2 rv[12];
    #pragma unroll
    for (int j = 0; j < 12; ++j) rv[j] = *addr[j];

    float4 acc = make_float4(0.f, 0.f, 0.f, 0.f);
    #pragma unroll
    for (int j = 0; j < 12; ++j) {
        const __half2 h0 = *reinterpret_cast<const __half2*>(&rv[j].x);
        const __half2 h1 = *reinterpret_cast<const __half2*>(&rv[j].y);
        const float2 f0 = __half22float2(h0);
        const float2 f1 = __half22float2(h1);
        acc.x += w[j] * f0.x;
        acc.y += w[j] * f0.y;
        acc.z += w[j] * f1.x;
        acc.w += w[j] * f1.y;
    }

    constexpr float third = 1.0f / 3.0f;
    acc.x *= third; acc.y *= third; acc.z *= third; acc.w *= third;

    float4* op = reinterpret_cast<float4*>(out + ((size_t)n * M + m) * Cc);
    op[chunk] = acc;
}

// ---------------------------------------------------------------------------
// Mid tier (ws fits planes only): unsorted fp16 gather (R3 kernel).
// ---------------------------------------------------------------------------
__global__ __launch_bounds__(256) void triplane_gather_hwc8h(
    const __half* __restrict__ tp, const float* __restrict__ coords,
    float* __restrict__ out, int M)
{
    const int gid   = blockIdx.x * 256 + threadIdx.x;
    const int m     = gid >> 3;
    const int chunk = gid & 7;
    const int n     = blockIdx.y;
    if (m >= M) return;

    const float* cp = coords + ((size_t)n * M + m) * 3;
    const float cx = cp[0], cy = cp[1], cz = cp[2];

    const uint2* addr[12];
    float w[12];

    #pragma unroll
    for (int p = 0; p < 3; ++p) {
        const float gxc = (p == 2) ? cz : cx;
        const float gyc = (p == 0) ? cy : ((p == 1) ? cz : cx);
        const float x = ((gxc + 1.0f) * 256.0f - 1.0f) * 0.5f;
        const float y = ((gyc + 1.0f) * 256.0f - 1.0f) * 0.5f;
        const float x0f = floorf(x), y0f = floorf(y);
        const float wx = x - x0f, wy = y - y0f;
        const int x0 = (int)x0f, y0 = (int)y0f;
        const int x1 = x0 + 1,   y1 = y0 + 1;
        const bool vx0 = (unsigned)x0 < 256u;
        const bool vx1 = (unsigned)x1 < 256u;
        const bool vy0 = (unsigned)y0 < 256u;
        const bool vy1 = (unsigned)y1 < 256u;
        const int cx0 = min(max(x0, 0), 255), cx1 = min(max(x1, 0), 255);
        const int cy0 = min(max(y0, 0), 255), cy1 = min(max(y1, 0), 255);

        w[p * 4 + 0] = ((vx0 && vy0) ? 1.f : 0.f) * (1.f - wx) * (1.f - wy);
        w[p * 4 + 1] = ((vx1 && vy0) ? 1.f : 0.f) * wx * (1.f - wy);
        w[p * 4 + 2] = ((vx0 && vy1) ? 1.f : 0.f) * (1.f - wx) * wy;
        w[p * 4 + 3] = ((vx1 && vy1) ? 1.f : 0.f) * wx * wy;

        const uint2* base = reinterpret_cast<const uint2*>(
            tp + (size_t)(n * 3 + p) * HWPIX * Cc);
        addr[p * 4 + 0] = base + (size_t)((cy0 << 8) + cx0) * 8 + chunk;
        addr[p * 4 + 1] = base + (size_t)((cy0 << 8) + cx1) * 8 + chunk;
        addr[p * 4 + 2] = base + (size_t)((cy1 << 8) + cx0) * 8 + chunk;
        addr[p * 4 + 3] = base + (size_t)((cy1 << 8) + cx1) * 8 + chunk;
    }

    uint2 rv[12];
    #pragma unroll
    for (int j = 0; j < 12; ++j) rv[j] = *addr[j];

    float4 acc = make_float4(0.f, 0.f, 0.f, 0.f);
    #pragma unroll
    for (int j = 0; j < 12; ++j) {
        const __half2 h0 = *reinterpret_cast<const __half2*>(&rv[j].x);
        const __half2 h1 = *reinterpret_cast<const __half2*>(&rv[j].y);
        const float2 f0 = __half22float2(h0);
        const float2 f1 = __half22float2(h1);
        acc.x += w[j] * f0.x;
        acc.y += w[j] * f0.y;
        acc.z += w[j] * f1.x;
        acc.w += w[j] * f1.y;
    }

    constexpr float third = 1.0f / 3.0f;
    acc.x *= third; acc.y *= third; acc.z *= third; acc.w *= third;

    float4* op = reinterpret_cast<float4*>(out + ((size_t)n * M + m) * Cc);
    op[chunk] = acc;
}

// ---------------------------------------------------------------------------
// Fallback (no workspace): gather straight from [C][H][W] f32 layout.
// ---------------------------------------------------------------------------
__global__ __launch_bounds__(256) void triplane_gather_chw(
    const float* __restrict__ planes, const float* __restrict__ coords,
    float* __restrict__ out, int M)
{
    const int m = blockIdx.x * 256 + threadIdx.x;
    const int n = blockIdx.y;
    if (m >= M) return;

    const float* cp = coords + ((size_t)n * M + m) * 3;
    const float cx = cp[0], cy = cp[1], cz = cp[2];

    int   off[3][4];
    float w[3][4];
    #pragma unroll
    for (int p = 0; p < 3; ++p) {
        const float gxc = (p == 2) ? cz : cx;
        const float gyc = (p == 0) ? cy : ((p == 1) ? cz : cx);
        const float x = ((gxc + 1.0f) * 256.0f - 1.0f) * 0.5f;
        const float y = ((gyc + 1.0f) * 256.0f - 1.0f) * 0.5f;
        const float x0f = floorf(x), y0f = floorf(y);
        const float wx = x - x0f, wy = y - y0f;
        const int x0 = (int)x0f, y0 = (int)y0f;
        const int x1 = x0 + 1,   y1 = y0 + 1;
        const bool vx0 = (unsigned)x0 < 256u, vx1 = (unsigned)x1 < 256u;
        const bool vy0 = (unsigned)y0 < 256u, vy1 = (unsigned)y1 < 256u;
        const int cx0 = min(max(x0, 0), 255), cx1 = min(max(x1, 0), 255);
        const int cy0 = min(max(y0, 0), 255), cy1 = min(max(y1, 0), 255);
        off[p][0] = (cy0 << 8) + cx0;  w[p][0] = ((vx0 && vy0) ? 1.f : 0.f) * (1.f - wx) * (1.f - wy);
        off[p][1] = (cy0 << 8) + cx1;  w[p][1] = ((vx1 && vy0) ? 1.f : 0.f) * wx * (1.f - wy);
        off[p][2] = (cy1 << 8) + cx0;  w[p][2] = ((vx0 && vy1) ? 1.f : 0.f) * (1.f - wx) * wy;
        off[p][3] = (cy1 << 8) + cx1;  w[p][3] = ((vx1 && vy1) ? 1.f : 0.f) * wx * wy;
    }

    float* op = out + ((size_t)n * M + m) * Cc;
    constexpr float third = 1.0f / 3.0f;
    for (int c = 0; c < Cc; ++c) {
        float a = 0.f;
        #pragma unroll
        for (int p = 0; p < 3; ++p) {
            const float* b = planes + ((size_t)(n * 3 + p) * Cc + c) * HWPIX;
            a += w[p][0] * b[off[p][0]] + w[p][1] * b[off[p][1]]
               + w[p][2] * b[off[p][2]] + w[p][3] * b[off[p][3]];
        }
        op[c] = a * third;
    }
}

extern "C" void kernel_launch(void* const* d_in, const int* in_sizes, int n_in,
                              void* d_out, int out_size, void* d_ws, size_t ws_size,
                              hipStream_t stream)
{
    const float* planes = (const float*)d_in[0];
    const float* coords = (const float*)d_in[1];
    float* out = (float*)d_out;

    const int M = in_sizes[1] / (Nn * 3);           // 500000

    const size_t tp_bytes   = (size_t)Nn * Pp * HWPIX * Cc * sizeof(__half);   // ~50 MB
    const size_t idx_bytes  = (size_t)Nn * M * sizeof(unsigned);               // ~8 MB
    const size_t hist_bytes = (size_t)Nn * NCELLS * sizeof(unsigned);          // 0.5 MB

    if (ws_size >= tp_bytes + idx_bytes + hist_bytes) {
        __half*   tp   = (__half*)d_ws;
        unsigned* idx  = (unsigned*)((char*)d_ws + tp_bytes);
        unsigned* hist = (unsigned*)((char*)d_ws + tp_bytes + idx_bytes);

        transpose_chw_hwc_h<<<dim3(HWPIX / 256, Nn * Pp), 256, 0, stream>>>(planes, tp);
        zero_u32<<<(Nn * NCELLS + 255) / 256, 256, 0, stream>>>(hist, Nn * NCELLS);
        hist_kernel<<<dim3((M + 255) / 256, Nn), 256, 0, stream>>>(coords, hist, M);
        scan_kernel<<<Nn, 1024, 0, stream>>>(hist);
        scatter_idx_kernel<<<dim3((M + 255) / 256, Nn), 256, 0, stream>>>(coords, hist, idx, M);

        const int gx  = (M * 8 + 255) / 256;   // 8 lanes per sample
        const int nwg = Nn * gx;
        triplane_gather_sorted<<<nwg, 256, 0, stream>>>(tp, idx, coords, out, M, gx, nwg);
    } else if (ws_size >= tp_bytes) {
        __half* tp = (__half*)d_ws;
        transpose_chw_hwc_h<<<dim3(HWPIX / 256, Nn * Pp), 256, 0, stream>>>(planes, tp);
        const int gx = (M * 8 + 255) / 256;
        triplane_gather_hwc8h<<<dim3(gx, Nn), 256, 0, stream>>>(tp, coords, out, M);
    } else {
        const int gx = (M + 255) / 256;
        triplane_gather_chw<<<dim3(gx, Nn), 256, 0, stream>>>(planes, coords, out, M);
    }
}